// Round 16
// baseline (261.318 us; speedup 1.0000x reference)
//
#include <hip/hip_runtime.h>

#define HID 256
#define SLOTS 30      // 30 u16 slots + u32 cnt = one 64B line per node
#define OVCAP 16384
#define NB 256        // blocks in histogram/scatter phases
typedef unsigned short ushort_t;
typedef unsigned int uint_t;
typedef __attribute__((ext_vector_type(8))) short short8;
typedef __attribute__((ext_vector_type(4))) float f32x4;
typedef __attribute__((ext_vector_type(4))) unsigned short us4;
typedef __attribute__((ext_vector_type(8))) unsigned short us8;

__device__ __forceinline__ ushort_t f2b(float f) {
    uint_t u = __float_as_uint(f);
    u = u + 0x7fffu + ((u >> 16) & 1u);   // RNE
    return (ushort_t)(u >> 16);
}

// ---------------- phase A: per-block bucket histogram (LDS atomics) || W-prep --------
__global__ __launch_bounds__(256) void k_histprep(const int* __restrict__ dst,
                                                  int* __restrict__ hist,
                                                  int E, int CH, int NBKT,
                                                  const float* __restrict__ W1,
                                                  ushort_t* __restrict__ Wt1,
                                                  const float* __restrict__ W2,
                                                  ushort_t* __restrict__ Wt2, int p1b) {
    int bid = blockIdx.x;
    int tid = threadIdx.x;
    if (bid < NB) {
        __shared__ int h[256];
        h[tid] = 0;
        __syncthreads();
        int e0 = bid * CH;
        for (int it = tid; it < CH; it += 256) {
            int e = e0 + it;
            if (e < E) atomicAdd(&h[dst[e] >> 8], 1);
        }
        __syncthreads();
        if (tid < NBKT) hist[tid * NB + bid] = h[tid];
        return;
    }
    const float* W = (bid < NB + p1b) ? W1 : W2;
    ushort_t* Wt = (bid < NB + p1b) ? Wt1 : Wt2;
    int kg = (bid < NB + p1b) ? (bid - NB) : (bid - NB - p1b);
    int c = tid;
    float v = W[(size_t)kg * HID + c];
    int p = kg >> 6;
    int k = kg & 63;
    int byte_ = c * 128 + k * 2;
    int slot = byte_ >> 4;
    int sw = (slot & ~7) | ((slot ^ c) & 7);
    size_t dst_byte = (size_t)p * 32768 + ((size_t)sw << 4) + (byte_ & 15);
    Wt[dst_byte >> 1] = f2b(v);
}

// ---------------- phase B: bucket bases + per-(bucket,block) offsets; ovn=0 ----------
__global__ __launch_bounds__(256) void k_scanb(const int* __restrict__ hist,
                                               int* __restrict__ offb,
                                               int* __restrict__ base,
                                               int* __restrict__ ovn, int NBKT) {
    __shared__ int s[256];
    int t = threadIdx.x;
    int sum = 0;
    if (t < NBKT) {
        const int* hp = hist + t * NB;
        for (int blk = 0; blk < NB; ++blk) sum += hp[blk];
    }
    s[t] = sum;
    __syncthreads();
#pragma unroll
    for (int d = 1; d < 256; d <<= 1) {
        int u = (t >= d) ? s[t - d] : 0;
        __syncthreads();
        s[t] += u;
        __syncthreads();
    }
    int myBase = s[t] - sum;
    if (t < NBKT) {
        base[t] = myBase;
        int run = myBase;
        const int* hp = hist + t * NB;
        int* op = offb + t * NB;
        for (int blk = 0; blk < NB; ++blk) { op[blk] = run; run += hp[blk]; }
    }
    if (t == 255) { base[NBKT] = s[255]; *ovn = 0; }
}

// ---------------- phase C: scatter edges to bucket-sorted order (LDS ranks) ----------
__global__ __launch_bounds__(256) void k_scatter(const int* __restrict__ src,
                                                 const int* __restrict__ dst,
                                                 const int* __restrict__ offb,
                                                 uint_t* __restrict__ scat,
                                                 int E, int CH) {
    __shared__ int h[256];
    int tid = threadIdx.x;
    int bid = blockIdx.x;
    h[tid] = 0;
    __syncthreads();
    int e0 = bid * CH;
    for (int it = tid; it < CH; it += 256) {
        int e = e0 + it;
        if (e < E) {
            int d = dst[e], sv = src[e];
            int b = d >> 8;
            int r = atomicAdd(&h[b], 1);
            scat[offb[b * NB + bid] + r] = ((uint_t)sv << 8) | (uint_t)(d & 255);
        }
    }
}

// ---------------- phase D: per-bucket CSR rows + dis + fused cast + DEGREE HIST ------
__global__ __launch_bounds__(256) void k_csr(const uint_t* __restrict__ scat,
                                             const int* __restrict__ base,
                                             ushort_t* __restrict__ csr2,
                                             float* __restrict__ dis,
                                             int* __restrict__ ovn,
                                             int2* __restrict__ ov,
                                             const float* __restrict__ x,
                                             ushort_t* __restrict__ xg,
                                             int* __restrict__ dhist, int n) {
    __shared__ ushort_t rows[256 * 32];   // 16 KB
    __shared__ int rc[256];
    __shared__ float sdis[256];
    __shared__ int dh[32];
    int tid = threadIdx.x;
    int b = blockIdx.x;
    rc[tid] = 0;
    if (tid < 32) dh[tid] = 0;
    uint4* r4 = (uint4*)rows;
#pragma unroll
    for (int k = tid; k < 1024; k += 256) r4[k] = make_uint4(0u, 0u, 0u, 0u);
    __syncthreads();
    int lo = base[b], hi = base[b + 1];
    for (int i = lo + tid; i < hi; i += 256) {
        uint_t p = scat[i];
        int local = (int)(p & 255u);
        int sv = (int)(p >> 8);
        int c = atomicAdd(&rc[local], 1);
        if (c < SLOTS) {
            rows[local * 32 + c] = (ushort_t)sv;
        } else {
            int q = atomicAdd(ovn, 1);
            if (q < OVCAP) ov[q] = make_int2(b * 256 + local, sv);
        }
    }
    __syncthreads();
    ((int*)(rows + tid * 32))[15] = rc[tid];
    float dv = rsqrtf((float)(rc[tid] + 1));
    sdis[tid] = dv;
    int node = b * 256 + tid;
    if (node < n) {
        dis[node] = dv;
        atomicAdd(&dh[min(rc[tid], 31)], 1);   // degree histogram (LDS)
    }
    __syncthreads();
    if (tid < 32) dhist[b * 32 + tid] = dh[tid];
    int node0 = b * 256;
    uint4* cg = (uint4*)csr2;
#pragma unroll
    for (int k = tid; k < 1024; k += 256) {
        int row = k >> 2, word = k & 3;
        if (node0 + row < n) cg[(size_t)(node0 + row) * 4 + word] = r4[row * 4 + word];
    }
    // fused cast: 256 nodes x 128 ch -> Xg grouped [4][n][32], dis-scaled
#pragma unroll
    for (int c = 0; c < 16; ++c) {
        int u = c * 256 + tid;
        int rl = u >> 4;
        int j = u & 15;
        int node2 = node0 + rl;
        if (node2 < n) {
            float dvv = sdis[rl];
            const float4* p = (const float4*)(x + (size_t)node2 * 128 + j * 8);
            float4 v0 = p[0], v1 = p[1];
            us8 o;
            o[0] = f2b(v0.x * dvv); o[1] = f2b(v0.y * dvv);
            o[2] = f2b(v0.z * dvv); o[3] = f2b(v0.w * dvv);
            o[4] = f2b(v1.x * dvv); o[5] = f2b(v1.y * dvv);
            o[6] = f2b(v1.z * dvv); o[7] = f2b(v1.w * dvv);
            size_t dst = (size_t)(j >> 2) * ((size_t)n * 32) + (size_t)node2 * 32
                         + (size_t)(j & 3) * 8;
            *(us8*)(xg + dst) = o;
        }
    }
}

// ---------------- degree-bin scan: bin bases + per-(bin,bucket) offsets --------------
__global__ __launch_bounds__(256) void k_dscan(const int* __restrict__ dhist,
                                               int* __restrict__ doffb, int NBKT) {
    __shared__ int s[32];
    int t = threadIdx.x;
    if (t < 32) {
        int sum = 0;
        for (int b = 0; b < NBKT; ++b) sum += dhist[b * 32 + t];
        s[t] = sum;
    }
    __syncthreads();
    if (t == 0) {
        int run = 0;
        for (int d = 0; d < 32; ++d) { int c = s[d]; s[d] = run; run += c; }
    }
    __syncthreads();
    if (t < 32) {
        int run = s[t];
        for (int b = 0; b < NBKT; ++b) { doffb[t * NBKT + b] = run; run += dhist[b * 32 + t]; }
    }
}

// ---------------- degree-sorted permutation scatter ----------------
__global__ __launch_bounds__(256) void k_dscat(const ushort_t* __restrict__ csr2,
                                               const int* __restrict__ doffb,
                                               int* __restrict__ perm, int n, int NBKT) {
    __shared__ int dh[32];
    int tid = threadIdx.x;
    int b = blockIdx.x;
    if (tid < 32) dh[tid] = 0;
    __syncthreads();
    int node = b * 256 + tid;
    if (node < n) {
        int deg = ((const int*)csr2)[node * 16 + 15];
        int bin = min(deg, 31);
        int r = atomicAdd(&dh[bin], 1);
        perm[doffb[bin * NBKT + b] + r] = node;
    }
}

// ---------------- grouped aggregation: 1 node/quarter, DEGREE-SORTED via perm --------
// All 4 quarters in a wave have equal/adjacent degree -> wave-uniform predicates.
#define ACC8(r)                                                            \
    a0 += __uint_as_float((r).x << 16); a1 += __uint_as_float((r).x & 0xffff0000u); \
    a2 += __uint_as_float((r).y << 16); a3 += __uint_as_float((r).y & 0xffff0000u); \
    a4 += __uint_as_float((r).z << 16); a5 += __uint_as_float((r).z & 0xffff0000u); \
    a6 += __uint_as_float((r).w << 16); a7 += __uint_as_float((r).w & 0xffff0000u);

template <int NG>
__global__ __launch_bounds__(256) void k_agg_g(const ushort_t* __restrict__ Yg,
                                               ushort_t* __restrict__ Z,
                                               const ushort_t* __restrict__ csr2,
                                               const int* __restrict__ ovn,
                                               const int2* __restrict__ ov,
                                               const float* __restrict__ dis,
                                               const int* __restrict__ perm, int n) {
    const int LOG = (NG == 8) ? 3 : 2;
    const int g = blockIdx.x & (NG - 1);
    const int chunk = blockIdx.x >> LOG;
    const int q = threadIdx.x >> 4;
    const int l16 = threadIdx.x & 15;
    const int pi = chunk * 16 + q;
    if (pi >= n) return;
    const int v = perm[pi];
    const int par = l16 >> 2;
    const int sub = l16 & 3;
    const uint4* Yb = (const uint4*)(Yg + (size_t)g * ((size_t)n * 32));
    const ushort_t* rowb = csr2 + (size_t)v * 32;
    const int deg = ((const int*)rowb)[15];
    const int lim = min(deg, SLOTS);
    const int base = par * 8;
    uint4 self = make_uint4(0u, 0u, 0u, 0u);
    if (par == 0) self = Yb[(uint_t)v * 4u + sub];
    float a0 = 0.f, a1 = 0.f, a2 = 0.f, a3 = 0.f, a4 = 0.f, a5 = 0.f, a6 = 0.f, a7 = 0.f;
    if (base < lim) {
        us8 idx = *(const us8*)(rowb + base);   // 8 indices, 1 aligned 16B load
        // branch-free 8-load burst (dummy slots hit node idx 0 -> L1-absorbed)
        uint4 r0 = Yb[(uint_t)idx[0] * 4u + sub];
        uint4 r1 = Yb[(uint_t)idx[1] * 4u + sub];
        uint4 r2 = Yb[(uint_t)idx[2] * 4u + sub];
        uint4 r3 = Yb[(uint_t)idx[3] * 4u + sub];
        uint4 r4 = Yb[(uint_t)idx[4] * 4u + sub];
        uint4 r5 = Yb[(uint_t)idx[5] * 4u + sub];
        uint4 r6 = Yb[(uint_t)idx[6] * 4u + sub];
        uint4 r7 = Yb[(uint_t)idx[7] * 4u + sub];
        if (base + 0 < lim) { ACC8(r0); }
        if (base + 1 < lim) { ACC8(r1); }
        if (base + 2 < lim) { ACC8(r2); }
        if (base + 3 < lim) { ACC8(r3); }
        if (base + 4 < lim) { ACC8(r4); }
        if (base + 5 < lim) { ACC8(r5); }
        if (base + 6 < lim) { ACC8(r6); }
        if (base + 7 < lim) { ACC8(r7); }
    }
    if (deg > SLOTS) {   // rare: scan tiny overflow list
        int m = min(*ovn, OVCAP);
        for (int i2 = par; i2 < m; i2 += 4) {
            int2 p = ov[i2];
            if (p.x == v) { uint4 r = Yb[(uint_t)p.y * 4u + sub]; ACC8(r); }
        }
    }
    a0 += __shfl_xor(a0, 4, 64); a1 += __shfl_xor(a1, 4, 64);
    a2 += __shfl_xor(a2, 4, 64); a3 += __shfl_xor(a3, 4, 64);
    a4 += __shfl_xor(a4, 4, 64); a5 += __shfl_xor(a5, 4, 64);
    a6 += __shfl_xor(a6, 4, 64); a7 += __shfl_xor(a7, 4, 64);
    a0 += __shfl_xor(a0, 8, 64); a1 += __shfl_xor(a1, 8, 64);
    a2 += __shfl_xor(a2, 8, 64); a3 += __shfl_xor(a3, 8, 64);
    a4 += __shfl_xor(a4, 8, 64); a5 += __shfl_xor(a5, 8, 64);
    a6 += __shfl_xor(a6, 8, 64); a7 += __shfl_xor(a7, 8, 64);
    if (par == 0) {
        ACC8(self);
        float dv = dis[v];
        us8 o;
        o[0] = f2b(a0 * dv); o[1] = f2b(a1 * dv); o[2] = f2b(a2 * dv); o[3] = f2b(a3 * dv);
        o[4] = f2b(a4 * dv); o[5] = f2b(a5 * dv); o[6] = f2b(a6 * dv); o[7] = f2b(a7 * dv);
        us8* zp = (us8*)(Z + (size_t)v * (NG * 32) + g * 32 + sub * 8);
        __builtin_nontemporal_store(o, zp);   // 64B-aligned full-line stream store
    }
}

// ---------------- MFMA GEMM: Yout[row][c] = bf16( post( A[row]·W[:,c] + bias[c] ) ) ----
template <int K, bool SCALE, bool OUTG>
__global__ __launch_bounds__(512) void k_gemm_mfma(const ushort_t* __restrict__ A,
                                                   const ushort_t* __restrict__ Wt,
                                                   const float* __restrict__ dis,
                                                   const float* __restrict__ bias,
                                                   ushort_t* __restrict__ Yout, int M) {
    __shared__ char lds[49152];
    char* As = lds;
    char* Bs = lds + 16384;
    const int tid = threadIdx.x;
    const int lane = tid & 63;
    const int w = tid >> 6;
    const int wm = w & 1;
    const int wn = w >> 1;
    const int row0 = blockIdx.x * 128;

    f32x4 acc[4][4];
#pragma unroll
    for (int i = 0; i < 4; ++i)
#pragma unroll
        for (int j = 0; j < 4; ++j) acc[i][j] = (f32x4){0.f, 0.f, 0.f, 0.f};

    for (int k0 = 0; k0 < K; k0 += 64) {
#pragma unroll
        for (int q = 0; q < 2; ++q) {
            int s = q * 512 + tid;
            int r = s >> 3;
            int kseg = (s & 7) ^ (r & 7);
            int row = row0 + r;
            if (row >= M) row = 0;
            const ushort_t* g = A + (size_t)row * K + k0 + kseg * 8;
            __builtin_amdgcn_global_load_lds((const uint_t*)g,
                                             (uint_t*)(As + q * 8192 + w * 1024), 16, 0, 0);
        }
        const ushort_t* gp = Wt + (size_t)(k0 >> 6) * (256 * 64);
#pragma unroll
        for (int q = 0; q < 4; ++q) {
            int s = q * 512 + tid;
            __builtin_amdgcn_global_load_lds((const uint_t*)(gp + (size_t)s * 8),
                                             (uint_t*)(Bs + q * 8192 + w * 1024), 16, 0, 0);
        }
        __syncthreads();
#pragma unroll
        for (int k32 = 0; k32 < 2; ++k32) {
            const int ksl = k32 * 4 + (lane >> 4);
            short8 wf[4], xf[4];
#pragma unroll
            for (int nn = 0; nn < 4; ++nn) {
                int col = wn * 64 + nn * 16 + (lane & 15);
                int slot = col * 8 + (ksl ^ (col & 7));
                wf[nn] = *(const short8*)(Bs + slot * 16);
            }
#pragma unroll
            for (int m = 0; m < 4; ++m) {
                int row = wm * 64 + m * 16 + (lane & 15);
                int slot = row * 8 + (ksl ^ (row & 7));
                xf[m] = *(const short8*)(As + slot * 16);
            }
#pragma unroll
            for (int nn = 0; nn < 4; ++nn)
#pragma unroll
                for (int m = 0; m < 4; ++m)
                    acc[nn][m] = __builtin_amdgcn_mfma_f32_16x16x32_bf16(wf[nn], xf[m],
                                                                         acc[nn][m], 0, 0, 0);
        }
        __syncthreads();
    }
    const int m_lo = lane & 15, c_hi = lane >> 4;
#pragma unroll
    for (int m = 0; m < 4; ++m) {
        int row = row0 + wm * 64 + m * 16 + m_lo;
        if (row < M) {
            float dv = SCALE ? dis[row] : 1.f;
#pragma unroll
            for (int nn = 0; nn < 4; ++nn) {
                int c0 = wn * 64 + nn * 16 + c_hi * 4;
                float4 bb = *(const float4*)(bias + c0);
                us4 o;
                o[0] = f2b(fmaxf(acc[nn][m][0] + bb.x, 0.f) * dv);
                o[1] = f2b(fmaxf(acc[nn][m][1] + bb.y, 0.f) * dv);
                o[2] = f2b(fmaxf(acc[nn][m][2] + bb.z, 0.f) * dv);
                o[3] = f2b(fmaxf(acc[nn][m][3] + bb.w, 0.f) * dv);
                size_t dst = OUTG
                    ? ((size_t)(c0 >> 5) * ((size_t)M * 32) + (size_t)row * 32 + (c0 & 31))
                    : ((size_t)row * HID + c0);
                *(us4*)(Yout + dst) = o;
            }
        }
    }
}

// ---------------- pooling: one block per graph, atomic-free, fused divide ------------
__global__ __launch_bounds__(256) void k_pool2(const ushort_t* __restrict__ H,
                                               const int* __restrict__ batch,
                                               float* __restrict__ out, int n) {
    __shared__ int se[2];
    int g = blockIdx.x;
    if (threadIdx.x < 2) {
        int tgt = g + (int)threadIdx.x;
        int lo = 0, hi = n;
        while (lo < hi) { int mid = (lo + hi) >> 1; if (batch[mid] < tgt) lo = mid + 1; else hi = mid; }
        se[threadIdx.x] = lo;
    }
    __syncthreads();
    int s = se[0], e = se[1];
    int c = threadIdx.x;
    float sum = 0.f;
    for (int i = s; i < e; ++i)
        sum += __uint_as_float(((uint_t)H[(size_t)i * HID + c]) << 16);
    out[(size_t)g * HID + c] = sum / (float)max(e - s, 1);
}

extern "C" void kernel_launch(void* const* d_in, const int* in_sizes, int n_in,
                              void* d_out, int out_size, void* d_ws, size_t ws_size,
                              hipStream_t stream) {
    const float* x = (const float*)d_in[0];
    const float* W1 = (const float*)d_in[1];
    const float* b1 = (const float*)d_in[2];
    const float* W2 = (const float*)d_in[3];
    const float* b2 = (const float*)d_in[4];
    const int* ei = (const int*)d_in[5];
    const int* batch = (const int*)d_in[6];
    float* out = (float*)d_out;

    const int N = in_sizes[6];        // 50000
    const int E = in_sizes[5] / 2;    // 800000
    const int K1 = in_sizes[0] / N;   // 128
    const int G = out_size / HID;     // 500
    (void)n_in; (void)ws_size;

    char* w = (char*)d_ws;
    int* ovn = (int*)(w + 0);                       // 1 i32 (zeroed by k_scanb)
    int2* ov = (int2*)(w + 64);                     // 16384 int2 -> ends 131136
    ushort_t* csr2 = (ushort_t*)(w + 131136);       // 50000 x 64B rows -> ends 3331136
    float* dis = (float*)(w + 3331136);             // -> 3531136
    ushort_t* Wt1 = (ushort_t*)(w + 3531136);       // -> 3596672
    ushort_t* Wt2 = (ushort_t*)(w + 3596672);       // -> 3727744
    ushort_t* Xg = (ushort_t*)(w + 3727744);        // grouped [4][N][32] -> 16527744
    ushort_t* Z1 = (ushort_t*)(w + 16527744);       // [N][128] -> 29327744
    ushort_t* H1g = (ushort_t*)(w + 29327744);      // grouped [8][N][32] -> 54927744
    ushort_t* Z2 = (ushort_t*)(w + 3727744);        // overlays Xg+Z1 (dead)
    ushort_t* H2 = (ushort_t*)(w + 29327744);       // overlays H1g (dead)
    int* hist = (int*)(w + 54927744);               // NBKT x NB i32
    int* offb = (int*)(w + 55128448);               // NBKT x NB i32
    int* base = (int*)(w + 55329152);               // NBKT+1 i32
    uint_t* scat = (uint_t*)(w + 55330048);         // E u32 -> 58530048
    int* dhist = (int*)(w + 58530048);              // NBKT x 32 i32 -> 58555136
    int* doffb = (int*)(w + 58555136);              // 32 x NBKT i32 -> 58580224
    int* perm = (int*)(w + 58580224);               // N i32 -> 58780224

    const int NBKT = (N + 255) >> 8;                // 196
    const int CH = (E + NB - 1) / NB;               // 3125
    k_histprep<<<NB + K1 + HID, 256, 0, stream>>>(ei + E, hist, E, CH, NBKT,
                                                  W1, Wt1, W2, Wt2, K1);
    k_scanb<<<1, 256, 0, stream>>>(hist, offb, base, ovn, NBKT);
    k_scatter<<<NB, 256, 0, stream>>>(ei, ei + E, offb, scat, E, CH);
    k_csr<<<NBKT, 256, 0, stream>>>(scat, base, csr2, dis, ovn, ov, x, Xg, dhist, N);
    k_dscan<<<1, 256, 0, stream>>>(dhist, doffb, NBKT);
    k_dscat<<<NBKT, 256, 0, stream>>>(csr2, doffb, perm, N, NBKT);

    int gblk = (N + 127) / 128;
    const int chunks16 = (N + 15) / 16;  // 3125
    k_agg_g<4><<<4 * chunks16, 256, 0, stream>>>(Xg, Z1, csr2, ovn, ov, dis, perm, N);
    k_gemm_mfma<128, true, true><<<gblk, 512, 0, stream>>>(Z1, Wt1, dis, b1, H1g, N);
    k_agg_g<8><<<8 * chunks16, 256, 0, stream>>>(H1g, Z2, csr2, ovn, ov, dis, perm, N);
    k_gemm_mfma<256, false, false><<<gblk, 512, 0, stream>>>(Z2, Wt2, dis, b2, H2, N);

    k_pool2<<<G, 256, 0, stream>>>(H2, batch, out, N);
}

// Round 17
// 202.543 us; speedup vs baseline: 1.2902x; 1.2902x over previous
//
#include <hip/hip_runtime.h>

#define HID 256
#define SLOTS 30      // 30 u16 slots + u32 cnt = one 64B line per node
#define OVCAP 16384
#define NB 256        // blocks in histogram/scatter phases
typedef unsigned short ushort_t;
typedef unsigned int uint_t;
typedef __attribute__((ext_vector_type(8))) short short8;
typedef __attribute__((ext_vector_type(4))) float f32x4;
typedef __attribute__((ext_vector_type(4))) unsigned short us4;
typedef __attribute__((ext_vector_type(8))) unsigned short us8;

__device__ __forceinline__ ushort_t f2b(float f) {
    uint_t u = __float_as_uint(f);
    u = u + 0x7fffu + ((u >> 16) & 1u);   // RNE
    return (ushort_t)(u >> 16);
}

// ---------------- phase A: per-block bucket histogram (LDS atomics) || W-prep --------
// bucket = dst >> 8 (256 nodes per bucket). hist[b][blk].
__global__ __launch_bounds__(256) void k_histprep(const int* __restrict__ dst,
                                                  int* __restrict__ hist,
                                                  int E, int CH, int NBKT,
                                                  const float* __restrict__ W1,
                                                  ushort_t* __restrict__ Wt1,
                                                  const float* __restrict__ W2,
                                                  ushort_t* __restrict__ Wt2, int p1b) {
    int bid = blockIdx.x;
    int tid = threadIdx.x;
    if (bid < NB) {
        __shared__ int h[256];
        h[tid] = 0;
        __syncthreads();
        int e0 = bid * CH;
        for (int it = tid; it < CH; it += 256) {
            int e = e0 + it;
            if (e < E) atomicAdd(&h[dst[e] >> 8], 1);
        }
        __syncthreads();
        if (tid < NBKT) hist[tid * NB + bid] = h[tid];
        return;
    }
    // -------- W prep (transposed bf16, K-panel-blocked, pre-swizzled) --------
    const float* W = (bid < NB + p1b) ? W1 : W2;
    ushort_t* Wt = (bid < NB + p1b) ? Wt1 : Wt2;
    int kg = (bid < NB + p1b) ? (bid - NB) : (bid - NB - p1b);
    int c = tid;
    float v = W[(size_t)kg * HID + c];
    int p = kg >> 6;
    int k = kg & 63;
    int byte_ = c * 128 + k * 2;
    int slot = byte_ >> 4;
    int sw = (slot & ~7) | ((slot ^ c) & 7);
    size_t dst_byte = (size_t)p * 32768 + ((size_t)sw << 4) + (byte_ & 15);
    Wt[dst_byte >> 1] = f2b(v);
}

// ---------------- phase B: bucket bases + per-(bucket,block) offsets; ovn=0 ----------
__global__ __launch_bounds__(256) void k_scanb(const int* __restrict__ hist,
                                               int* __restrict__ offb,
                                               int* __restrict__ base,
                                               int* __restrict__ ovn, int NBKT) {
    __shared__ int s[256];
    int t = threadIdx.x;
    int sum = 0;
    if (t < NBKT) {
        const int* hp = hist + t * NB;
        for (int blk = 0; blk < NB; ++blk) sum += hp[blk];
    }
    s[t] = sum;
    __syncthreads();
#pragma unroll
    for (int d = 1; d < 256; d <<= 1) {
        int u = (t >= d) ? s[t - d] : 0;
        __syncthreads();
        s[t] += u;
        __syncthreads();
    }
    int myBase = s[t] - sum;   // exclusive
    if (t < NBKT) {
        base[t] = myBase;
        int run = myBase;
        const int* hp = hist + t * NB;
        int* op = offb + t * NB;
        for (int blk = 0; blk < NB; ++blk) { op[blk] = run; run += hp[blk]; }
    }
    if (t == 255) { base[NBKT] = s[255]; *ovn = 0; }
}

// ---------------- phase C: scatter edges to bucket-sorted order (LDS ranks) ----------
// packed u32 = (src << 8) | (dst & 255)
__global__ __launch_bounds__(256) void k_scatter(const int* __restrict__ src,
                                                 const int* __restrict__ dst,
                                                 const int* __restrict__ offb,
                                                 uint_t* __restrict__ scat,
                                                 int E, int CH) {
    __shared__ int h[256];
    int tid = threadIdx.x;
    int bid = blockIdx.x;
    h[tid] = 0;
    __syncthreads();
    int e0 = bid * CH;
    for (int it = tid; it < CH; it += 256) {
        int e = e0 + it;
        if (e < E) {
            int d = dst[e], sv = src[e];
            int b = d >> 8;
            int r = atomicAdd(&h[b], 1);
            scat[offb[b * NB + bid] + r] = ((uint_t)sv << 8) | (uint_t)(d & 255);
        }
    }
}

// ---------------- phase D: per-bucket CSR rows in LDS + dis + FUSED x->Xg cast -------
__global__ __launch_bounds__(256) void k_csr(const uint_t* __restrict__ scat,
                                             const int* __restrict__ base,
                                             ushort_t* __restrict__ csr2,
                                             float* __restrict__ dis,
                                             int* __restrict__ ovn,
                                             int2* __restrict__ ov,
                                             const float* __restrict__ x,
                                             ushort_t* __restrict__ xg, int n) {
    __shared__ ushort_t rows[256 * 32];   // 16 KB
    __shared__ int rc[256];
    __shared__ float sdis[256];
    int tid = threadIdx.x;
    int b = blockIdx.x;
    rc[tid] = 0;
    uint4* r4 = (uint4*)rows;
#pragma unroll
    for (int k = tid; k < 1024; k += 256) r4[k] = make_uint4(0u, 0u, 0u, 0u);
    __syncthreads();
    int lo = base[b], hi = base[b + 1];
    for (int i = lo + tid; i < hi; i += 256) {
        uint_t p = scat[i];
        int local = (int)(p & 255u);
        int sv = (int)(p >> 8);
        int c = atomicAdd(&rc[local], 1);
        if (c < SLOTS) {
            rows[local * 32 + c] = (ushort_t)sv;
        } else {
            int q = atomicAdd(ovn, 1);
            if (q < OVCAP) ov[q] = make_int2(b * 256 + local, sv);
        }
    }
    __syncthreads();
    // embed cnt at bytes 60..63 of own row; dis to LDS + global
    ((int*)(rows + tid * 32))[15] = rc[tid];
    float dv = rsqrtf((float)(rc[tid] + 1));
    sdis[tid] = dv;
    int node = b * 256 + tid;
    if (node < n) dis[node] = dv;
    __syncthreads();
    // coalesced 64B-row writes
    int node0 = b * 256;
    uint4* cg = (uint4*)csr2;
#pragma unroll
    for (int k = tid; k < 1024; k += 256) {
        int row = k >> 2, word = k & 3;
        if (node0 + row < n) cg[(size_t)(node0 + row) * 4 + word] = r4[row * 4 + word];
    }
    // fused cast: 256 nodes x 128 ch -> Xg grouped [4][n][32], dis-scaled.
#pragma unroll
    for (int c = 0; c < 16; ++c) {
        int u = c * 256 + tid;
        int rl = u >> 4;              // node local
        int j = u & 15;               // which us8 in the row
        int node2 = node0 + rl;
        if (node2 < n) {
            float dvv = sdis[rl];
            const float4* p = (const float4*)(x + (size_t)node2 * 128 + j * 8);
            float4 v0 = p[0], v1 = p[1];
            us8 o;
            o[0] = f2b(v0.x * dvv); o[1] = f2b(v0.y * dvv);
            o[2] = f2b(v0.z * dvv); o[3] = f2b(v0.w * dvv);
            o[4] = f2b(v1.x * dvv); o[5] = f2b(v1.y * dvv);
            o[6] = f2b(v1.z * dvv); o[7] = f2b(v1.w * dvv);
            size_t dst = (size_t)(j >> 2) * ((size_t)n * 32) + (size_t)node2 * 32
                         + (size_t)(j & 3) * 8;
            *(us8*)(xg + dst) = o;
        }
    }
}

// ---------------- grouped aggregation: 2 nodes/quarter, branch-free gather bursts ----
#define ACC8(r)                                                            \
    a0 += __uint_as_float((r).x << 16); a1 += __uint_as_float((r).x & 0xffff0000u); \
    a2 += __uint_as_float((r).y << 16); a3 += __uint_as_float((r).y & 0xffff0000u); \
    a4 += __uint_as_float((r).z << 16); a5 += __uint_as_float((r).z & 0xffff0000u); \
    a6 += __uint_as_float((r).w << 16); a7 += __uint_as_float((r).w & 0xffff0000u);

#define ACC8B(r)                                                           \
    b0 += __uint_as_float((r).x << 16); b1 += __uint_as_float((r).x & 0xffff0000u); \
    b2 += __uint_as_float((r).y << 16); b3 += __uint_as_float((r).y & 0xffff0000u); \
    b4 += __uint_as_float((r).z << 16); b5 += __uint_as_float((r).z & 0xffff0000u); \
    b6 += __uint_as_float((r).w << 16); b7 += __uint_as_float((r).w & 0xffff0000u);

template <int NG>
__global__ __launch_bounds__(256) void k_agg_g(const ushort_t* __restrict__ Yg,
                                               ushort_t* __restrict__ Z,
                                               const ushort_t* __restrict__ csr2,
                                               const int* __restrict__ ovn,
                                               const int2* __restrict__ ov,
                                               const float* __restrict__ dis, int n) {
    const int LOG = (NG == 8) ? 3 : 2;
    const int g = blockIdx.x & (NG - 1);
    const int chunk = blockIdx.x >> LOG;
    const int q = threadIdx.x >> 4;
    const int l16 = threadIdx.x & 15;
    const int par = l16 >> 2;
    const int sub = l16 & 3;
    const int v0 = chunk * 32 + q * 2;
    if (v0 >= n) return;
    const int v1 = v0 + 1;
    const bool has1 = (v1 < n);
    const uint4* Yb = (const uint4*)(Yg + (size_t)g * ((size_t)n * 32));
    const ushort_t* rowb0 = csr2 + (size_t)v0 * 32;
    const ushort_t* rowb1 = csr2 + (size_t)v1 * 32;
    const int deg0 = ((const int*)rowb0)[15];
    const int deg1 = has1 ? ((const int*)rowb1)[15] : 0;
    const int lim0 = min(deg0, SLOTS);
    const int lim1 = min(deg1, SLOTS);
    const int base = par * 8;
    us8 idx0 = *(const us8*)(rowb0 + base);
    us8 idx1 = {};
    if (has1) idx1 = *(const us8*)(rowb1 + base);
    uint4 self0 = make_uint4(0u, 0u, 0u, 0u), self1 = make_uint4(0u, 0u, 0u, 0u);
    if (par == 0) self0 = Yb[(uint_t)v0 * 4u + sub];
    if (has1 && par == 1) self1 = Yb[(uint_t)v1 * 4u + sub];

    const bool g0 = base < lim0;
    const bool g1 = has1 && (base < lim1);
    uint4 r0, r1, r2, r3, r4, r5, r6, r7;
    uint4 s0, s1, s2, s3, s4, s5, s6, s7;
    if (g0) {
        r0 = Yb[(uint_t)idx0[0] * 4u + sub]; r1 = Yb[(uint_t)idx0[1] * 4u + sub];
        r2 = Yb[(uint_t)idx0[2] * 4u + sub]; r3 = Yb[(uint_t)idx0[3] * 4u + sub];
        r4 = Yb[(uint_t)idx0[4] * 4u + sub]; r5 = Yb[(uint_t)idx0[5] * 4u + sub];
        r6 = Yb[(uint_t)idx0[6] * 4u + sub]; r7 = Yb[(uint_t)idx0[7] * 4u + sub];
    }
    if (g1) {
        s0 = Yb[(uint_t)idx1[0] * 4u + sub]; s1 = Yb[(uint_t)idx1[1] * 4u + sub];
        s2 = Yb[(uint_t)idx1[2] * 4u + sub]; s3 = Yb[(uint_t)idx1[3] * 4u + sub];
        s4 = Yb[(uint_t)idx1[4] * 4u + sub]; s5 = Yb[(uint_t)idx1[5] * 4u + sub];
        s6 = Yb[(uint_t)idx1[6] * 4u + sub]; s7 = Yb[(uint_t)idx1[7] * 4u + sub];
    }
    float a0 = 0.f, a1 = 0.f, a2 = 0.f, a3 = 0.f, a4 = 0.f, a5 = 0.f, a6 = 0.f, a7 = 0.f;
    float b0 = 0.f, b1 = 0.f, b2 = 0.f, b3 = 0.f, b4 = 0.f, b5 = 0.f, b6 = 0.f, b7 = 0.f;
    if (g0) {
        if (base + 0 < lim0) { ACC8(r0); }
        if (base + 1 < lim0) { ACC8(r1); }
        if (base + 2 < lim0) { ACC8(r2); }
        if (base + 3 < lim0) { ACC8(r3); }
        if (base + 4 < lim0) { ACC8(r4); }
        if (base + 5 < lim0) { ACC8(r5); }
        if (base + 6 < lim0) { ACC8(r6); }
        if (base + 7 < lim0) { ACC8(r7); }
    }
    if (g1) {
        if (base + 0 < lim1) { ACC8B(s0); }
        if (base + 1 < lim1) { ACC8B(s1); }
        if (base + 2 < lim1) { ACC8B(s2); }
        if (base + 3 < lim1) { ACC8B(s3); }
        if (base + 4 < lim1) { ACC8B(s4); }
        if (base + 5 < lim1) { ACC8B(s5); }
        if (base + 6 < lim1) { ACC8B(s6); }
        if (base + 7 < lim1) { ACC8B(s7); }
    }
    if (deg0 > SLOTS) {
        int m = min(*ovn, OVCAP);
        for (int i2 = par; i2 < m; i2 += 4) {
            int2 p = ov[i2];
            if (p.x == v0) { uint4 r = Yb[(uint_t)p.y * 4u + sub]; ACC8(r); }
        }
    }
    if (deg1 > SLOTS) {
        int m = min(*ovn, OVCAP);
        for (int i2 = par; i2 < m; i2 += 4) {
            int2 p = ov[i2];
            if (p.x == v1) { uint4 r = Yb[(uint_t)p.y * 4u + sub]; ACC8B(r); }
        }
    }
    a0 += __shfl_xor(a0, 4, 64); a1 += __shfl_xor(a1, 4, 64);
    a2 += __shfl_xor(a2, 4, 64); a3 += __shfl_xor(a3, 4, 64);
    a4 += __shfl_xor(a4, 4, 64); a5 += __shfl_xor(a5, 4, 64);
    a6 += __shfl_xor(a6, 4, 64); a7 += __shfl_xor(a7, 4, 64);
    a0 += __shfl_xor(a0, 8, 64); a1 += __shfl_xor(a1, 8, 64);
    a2 += __shfl_xor(a2, 8, 64); a3 += __shfl_xor(a3, 8, 64);
    a4 += __shfl_xor(a4, 8, 64); a5 += __shfl_xor(a5, 8, 64);
    a6 += __shfl_xor(a6, 8, 64); a7 += __shfl_xor(a7, 8, 64);
    b0 += __shfl_xor(b0, 4, 64); b1 += __shfl_xor(b1, 4, 64);
    b2 += __shfl_xor(b2, 4, 64); b3 += __shfl_xor(b3, 4, 64);
    b4 += __shfl_xor(b4, 4, 64); b5 += __shfl_xor(b5, 4, 64);
    b6 += __shfl_xor(b6, 4, 64); b7 += __shfl_xor(b7, 4, 64);
    b0 += __shfl_xor(b0, 8, 64); b1 += __shfl_xor(b1, 8, 64);
    b2 += __shfl_xor(b2, 8, 64); b3 += __shfl_xor(b3, 8, 64);
    b4 += __shfl_xor(b4, 8, 64); b5 += __shfl_xor(b5, 8, 64);
    b6 += __shfl_xor(b6, 8, 64); b7 += __shfl_xor(b7, 8, 64);
    if (par == 0) {
        ACC8(self0);
        float dv = dis[v0];
        us8 o;
        o[0] = f2b(a0 * dv); o[1] = f2b(a1 * dv); o[2] = f2b(a2 * dv); o[3] = f2b(a3 * dv);
        o[4] = f2b(a4 * dv); o[5] = f2b(a5 * dv); o[6] = f2b(a6 * dv); o[7] = f2b(a7 * dv);
        us8* zp = (us8*)(Z + (size_t)v0 * (NG * 32) + g * 32 + sub * 8);
        __builtin_nontemporal_store(o, zp);
    }
    if (has1 && par == 1) {
        ACC8B(self1);
        float dv = dis[v1];
        us8 o;
        o[0] = f2b(b0 * dv); o[1] = f2b(b1 * dv); o[2] = f2b(b2 * dv); o[3] = f2b(b3 * dv);
        o[4] = f2b(b4 * dv); o[5] = f2b(b5 * dv); o[6] = f2b(b6 * dv); o[7] = f2b(b7 * dv);
        us8* zp = (us8*)(Z + (size_t)v1 * (NG * 32) + g * 32 + sub * 8);
        __builtin_nontemporal_store(o, zp);
    }
}

// ---------------- MFMA GEMM: Yout[row][c] = bf16( post( A[row]·W[:,c] + bias[c] ) ) ----
template <int K, bool SCALE, bool OUTG>
__global__ __launch_bounds__(512) void k_gemm_mfma(const ushort_t* __restrict__ A,
                                                   const ushort_t* __restrict__ Wt,
                                                   const float* __restrict__ dis,
                                                   const float* __restrict__ bias,
                                                   ushort_t* __restrict__ Yout, int M) {
    __shared__ char lds[49152];
    char* As = lds;
    char* Bs = lds + 16384;
    const int tid = threadIdx.x;
    const int lane = tid & 63;
    const int w = tid >> 6;
    const int wm = w & 1;
    const int wn = w >> 1;
    const int row0 = blockIdx.x * 128;

    f32x4 acc[4][4];
#pragma unroll
    for (int i = 0; i < 4; ++i)
#pragma unroll
        for (int j = 0; j < 4; ++j) acc[i][j] = (f32x4){0.f, 0.f, 0.f, 0.f};

    for (int k0 = 0; k0 < K; k0 += 64) {
#pragma unroll
        for (int q = 0; q < 2; ++q) {
            int s = q * 512 + tid;
            int r = s >> 3;
            int kseg = (s & 7) ^ (r & 7);
            int row = row0 + r;
            if (row >= M) row = 0;
            const ushort_t* g = A + (size_t)row * K + k0 + kseg * 8;
            __builtin_amdgcn_global_load_lds((const uint_t*)g,
                                             (uint_t*)(As + q * 8192 + w * 1024), 16, 0, 0);
        }
        const ushort_t* gp = Wt + (size_t)(k0 >> 6) * (256 * 64);
#pragma unroll
        for (int q = 0; q < 4; ++q) {
            int s = q * 512 + tid;
            __builtin_amdgcn_global_load_lds((const uint_t*)(gp + (size_t)s * 8),
                                             (uint_t*)(Bs + q * 8192 + w * 1024), 16, 0, 0);
        }
        __syncthreads();
#pragma unroll
        for (int k32 = 0; k32 < 2; ++k32) {
            const int ksl = k32 * 4 + (lane >> 4);
            short8 wf[4], xf[4];
#pragma unroll
            for (int nn = 0; nn < 4; ++nn) {
                int col = wn * 64 + nn * 16 + (lane & 15);
                int slot = col * 8 + (ksl ^ (col & 7));
                wf[nn] = *(const short8*)(Bs + slot * 16);
            }
#pragma unroll
            for (int m = 0; m < 4; ++m) {
                int row = wm * 64 + m * 16 + (lane & 15);
                int slot = row * 8 + (ksl ^ (row & 7));
                xf[m] = *(const short8*)(As + slot * 16);
            }
#pragma unroll
            for (int nn = 0; nn < 4; ++nn)
#pragma unroll
                for (int m = 0; m < 4; ++m)
                    acc[nn][m] = __builtin_amdgcn_mfma_f32_16x16x32_bf16(wf[nn], xf[m],
                                                                         acc[nn][m], 0, 0, 0);
        }
        __syncthreads();
    }
    const int m_lo = lane & 15, c_hi = lane >> 4;
#pragma unroll
    for (int m = 0; m < 4; ++m) {
        int row = row0 + wm * 64 + m * 16 + m_lo;
        if (row < M) {
            float dv = SCALE ? dis[row] : 1.f;
#pragma unroll
            for (int nn = 0; nn < 4; ++nn) {
                int c0 = wn * 64 + nn * 16 + c_hi * 4;
                float4 bb = *(const float4*)(bias + c0);
                us4 o;
                o[0] = f2b(fmaxf(acc[nn][m][0] + bb.x, 0.f) * dv);
                o[1] = f2b(fmaxf(acc[nn][m][1] + bb.y, 0.f) * dv);
                o[2] = f2b(fmaxf(acc[nn][m][2] + bb.z, 0.f) * dv);
                o[3] = f2b(fmaxf(acc[nn][m][3] + bb.w, 0.f) * dv);
                size_t dst = OUTG
                    ? ((size_t)(c0 >> 5) * ((size_t)M * 32) + (size_t)row * 32 + (c0 & 31))
                    : ((size_t)row * HID + c0);
                *(us4*)(Yout + dst) = o;
            }
        }
    }
}

// ---------------- pooling: one block per graph, atomic-free, fused divide ------------
__global__ __launch_bounds__(256) void k_pool2(const ushort_t* __restrict__ H,
                                               const int* __restrict__ batch,
                                               float* __restrict__ out, int n) {
    __shared__ int se[2];
    int g = blockIdx.x;
    if (threadIdx.x < 2) {
        int tgt = g + (int)threadIdx.x;
        int lo = 0, hi = n;
        while (lo < hi) { int mid = (lo + hi) >> 1; if (batch[mid] < tgt) lo = mid + 1; else hi = mid; }
        se[threadIdx.x] = lo;
    }
    __syncthreads();
    int s = se[0], e = se[1];
    int c = threadIdx.x;
    float sum = 0.f;
    for (int i = s; i < e; ++i)
        sum += __uint_as_float(((uint_t)H[(size_t)i * HID + c]) << 16);
    out[(size_t)g * HID + c] = sum / (float)max(e - s, 1);
}

extern "C" void kernel_launch(void* const* d_in, const int* in_sizes, int n_in,
                              void* d_out, int out_size, void* d_ws, size_t ws_size,
                              hipStream_t stream) {
    const float* x = (const float*)d_in[0];
    const float* W1 = (const float*)d_in[1];
    const float* b1 = (const float*)d_in[2];
    const float* W2 = (const float*)d_in[3];
    const float* b2 = (const float*)d_in[4];
    const int* ei = (const int*)d_in[5];
    const int* batch = (const int*)d_in[6];
    float* out = (float*)d_out;

    const int N = in_sizes[6];        // 50000
    const int E = in_sizes[5] / 2;    // 800000
    const int K1 = in_sizes[0] / N;   // 128
    const int G = out_size / HID;     // 500
    (void)n_in; (void)ws_size; (void)K1;

    char* w = (char*)d_ws;
    int* ovn = (int*)(w + 0);                       // 1 i32 (zeroed by k_scanb)
    int2* ov = (int2*)(w + 64);                     // 16384 int2 -> ends 131136
    ushort_t* csr2 = (ushort_t*)(w + 131136);       // 50000 x 64B rows -> ends 3331136
    float* dis = (float*)(w + 3331136);             // 50000 f32 -> 3531136
    ushort_t* Wt1 = (ushort_t*)(w + 3531136);       // -> 3596672
    ushort_t* Wt2 = (ushort_t*)(w + 3596672);       // -> 3727744
    ushort_t* Xg = (ushort_t*)(w + 3727744);        // grouped [4][N][32] -> 16527744
    ushort_t* Z1 = (ushort_t*)(w + 16527744);       // [N][128] -> 29327744
    ushort_t* H1g = (ushort_t*)(w + 29327744);      // grouped [8][N][32] -> 54927744
    ushort_t* Z2 = (ushort_t*)(w + 3727744);        // overlays Xg+Z1 (dead)
    ushort_t* H2 = (ushort_t*)(w + 29327744);       // overlays H1g (dead)
    int* hist = (int*)(w + 54927744);               // NBKT x NB i32
    int* offb = (int*)(w + 55128448);               // NBKT x NB i32
    int* base = (int*)(w + 55329152);               // NBKT+1 i32
    uint_t* scat = (uint_t*)(w + 55330048);         // E u32

    const int NBKT = (N + 255) >> 8;                // 196
    const int CH = (E + NB - 1) / NB;               // 3125
    // A: histogram + W-preps
    k_histprep<<<NB + K1 + HID, 256, 0, stream>>>(ei + E, hist, E, CH, NBKT,
                                                  W1, Wt1, W2, Wt2, K1);
    // B: scan (+ ovn=0)
    k_scanb<<<1, 256, 0, stream>>>(hist, offb, base, ovn, NBKT);
    // C: scatter to bucket-sorted order
    k_scatter<<<NB, 256, 0, stream>>>(ei, ei + E, offb, scat, E, CH);
    // D: per-bucket CSR rows + dis + fused dis-scaled x->Xg cast
    k_csr<<<NBKT, 256, 0, stream>>>(scat, base, csr2, dis, ovn, ov, x, Xg, N);

    int gblk = (N + 127) / 128;
    const int chunks32 = (N + 31) / 32;  // 1563
    k_agg_g<4><<<4 * chunks32, 256, 0, stream>>>(Xg, Z1, csr2, ovn, ov, dis, N);
    k_gemm_mfma<128, true, true><<<gblk, 512, 0, stream>>>(Z1, Wt1, dis, b1, H1g, N);
    k_agg_g<8><<<8 * chunks32, 256, 0, stream>>>(H1g, Z2, csr2, ovn, ov, dis, N);
    k_gemm_mfma<256, false, false><<<gblk, 512, 0, stream>>>(Z2, Wt2, dis, b2, H2, N);

    k_pool2<<<G, 256, 0, stream>>>(H2, batch, out, N);
}